// Round 11
// baseline (176.112 us; speedup 1.0000x reference)
//
#include <hip/hip_runtime.h>
#include <math.h>

typedef unsigned short u16;
typedef unsigned int u32;
typedef unsigned long long u64;
typedef __attribute__((ext_vector_type(8))) short short8;
typedef __attribute__((ext_vector_type(4))) float f32x4;
typedef __attribute__((ext_vector_type(4))) u16 u16x4;
typedef __attribute__((ext_vector_type(4))) u32 u32x4;
typedef __attribute__((ext_vector_type(8))) u16 u16x8;

#define AS1 __attribute__((address_space(1)))
#define AS3 __attribute__((address_space(3)))

// 0.125 * log2(e): QK^T scores scaled so softmax = exp2
#define QSCALE 0.18033688011112042f

__device__ __forceinline__ u16 f2bf(float f) {
  union { float f; u32 i; } u; u.f = f;
  u32 r = u.i + 0x7FFFu + ((u.i >> 16) & 1u);
  return (u16)(r >> 16);
}

__device__ __forceinline__ u32 pk_bf16(float a, float b) {
  u32 r;
  asm volatile("v_cvt_pk_bf16_f32 %0, %1, %2" : "=v"(r) : "v"(a), "v"(b));
  return r;
}

__device__ __forceinline__ void gl_lds16(const void* g, void* l) {
  __builtin_amdgcn_global_load_lds((const AS1 u32*)g, (AS3 u32*)l, 16, 0, 0);
}

#define MFMA32(a, b, c) __builtin_amdgcn_mfma_f32_16x16x32_bf16(a, b, c, 0, 0, 0)

// ---------------- RoPE table ----------------
__global__ void rope_table(float* __restrict__ cosT, float* __restrict__ sinT, int T) {
  int i = blockIdx.x * 256 + threadIdx.x;
  if (i >= T * 32) return;
  int t = i >> 5, j = i & 31;
  float inv = powf(10000.0f, -(float)j / 32.0f);
  float ang = (float)t * inv;
  cosT[i] = cosf(ang);
  sinT[i] = sinf(ang);
}

// ---------------- fused fp32 -> bf16 convert (x + 4 weights) ----------------
__global__ void cvt_all(const float* __restrict__ x,
                        const float* __restrict__ Wq, const float* __restrict__ Wk,
                        const float* __restrict__ Wv, const float* __restrict__ Wp,
                        u16* __restrict__ xb,
                        u16* __restrict__ Wqb, u16* __restrict__ Wkb,
                        u16* __restrict__ Wvb, u16* __restrict__ Wpb,
                        int n4x) {
  int i = blockIdx.x * 256 + threadIdx.x;
  const float* src; u16* dst; int off;
  if (i < n4x) { src = x; dst = xb; off = i; }
  else {
    int wi = i - n4x;
    int sel = wi >> 18;            // CC/4 = 2^18
    off = wi & ((1 << 18) - 1);
    src = sel == 0 ? Wq : sel == 1 ? Wk : sel == 2 ? Wv : Wp;
    dst = sel == 0 ? Wqb : sel == 1 ? Wkb : sel == 2 ? Wvb : Wpb;
  }
  float4 v = ((const float4*)src)[off];
  u16x4 o = { f2bf(v.x), f2bf(v.y), f2bf(v.z), f2bf(v.w) };
  ((u16x4*)dst)[off] = o;
}

// ---------------- fused QKV GEMM (bf16 MFMA) with RoPE epilogue ----------------
__global__ __launch_bounds__(256, 2) void gemm_qkv(
    const u16* __restrict__ xb,
    const u16* __restrict__ Wqb, const u16* __restrict__ Wkb, const u16* __restrict__ Wvb,
    const float* __restrict__ bq, const float* __restrict__ bk, const float* __restrict__ bv,
    const float* __restrict__ cosT, const float* __restrict__ sinT,
    u16* __restrict__ Qb, u16* __restrict__ Kb, u16* __restrict__ Vb) {
  const int K = 1024, N = 1024;
  __shared__ __attribute__((aligned(16))) u16 As[128 * 32];
  __shared__ __attribute__((aligned(16))) u16 Bs[128 * 32];
  const int tid = threadIdx.x;
  const int lane = tid & 63;
  const int hi = lane >> 4, cc = lane & 15;
  const int w = tid >> 6, wm = w >> 1, wn = w & 1;
  const int sel = blockIdx.x >> 3;
  const int row0 = blockIdx.y * 128, col0 = (blockIdx.x & 7) * 128;
  const u16* W = sel == 0 ? Wqb : sel == 1 ? Wkb : Wvb;
  const float* bias = sel == 0 ? bq : sel == 1 ? bk : bv;
  u16* Out = sel == 0 ? Qb : sel == 1 ? Kb : Vb;

  const int lr = tid >> 2;
  const int lk = (tid & 3) * 8;
  const u16* Ag0 = xb + (size_t)(row0 + lr) * K + lk;
  const u16* Ag1 = xb + (size_t)(row0 + 64 + lr) * K + lk;
  const u16* Wg0 = W + (size_t)(col0 + lr) * K + lk;
  const u16* Wg1 = W + (size_t)(col0 + 64 + lr) * K + lk;
  u16* Al0 = As + tid * 8;
  u16* Al1 = As + 2048 + tid * 8;
  u16* Bl0 = Bs + tid * 8;
  u16* Bl1 = Bs + 2048 + tid * 8;

  f32x4 acc[4][4];
#pragma unroll
  for (int m = 0; m < 4; ++m)
#pragma unroll
    for (int n = 0; n < 4; ++n) acc[m][n] = f32x4{0.f, 0.f, 0.f, 0.f};

  for (int k0 = 0; k0 < K; k0 += 32) {
    __syncthreads();
    gl_lds16(Ag0 + k0, Al0);
    gl_lds16(Ag1 + k0, Al1);
    gl_lds16(Wg0 + k0, Bl0);
    gl_lds16(Wg1 + k0, Bl1);
    __syncthreads();
    short8 a[4], b[4];
#pragma unroll
    for (int m = 0; m < 4; ++m)
      a[m] = *(const short8*)(As + (wm * 64 + m * 16 + cc) * 32 + hi * 8);
#pragma unroll
    for (int n = 0; n < 4; ++n)
      b[n] = *(const short8*)(Bs + (wn * 64 + n * 16 + cc) * 32 + hi * 8);
#pragma unroll
    for (int m = 0; m < 4; ++m)
#pragma unroll
      for (int n = 0; n < 4; ++n)
        acc[m][n] = MFMA32(a[m], b[n], acc[m][n]);
  }

  if (sel < 2) {
    const float qs = (sel == 0) ? QSCALE : 1.0f;
#pragma unroll
    for (int n = 0; n < 4; ++n) {
      const int col = col0 + wn * 64 + n * 16 + cc;
      const int j = (col & 63) >> 1;
      const float bb = bias[col];
#pragma unroll
      for (int m = 0; m < 4; ++m) {
        const int rw = row0 + wm * 64 + m * 16 + hi * 4;
#pragma unroll
        for (int r = 0; r < 4; ++r) {
          const int row = rw + r;
          const int t = row & 2047;
          float v = acc[m][n][r] + bb;
          float pv = __shfl_xor(v, 1);
          float c = cosT[t * 32 + j], s = sinT[t * 32 + j];
          float oo = (cc & 1) ? (s * pv + c * v) : (c * v - s * pv);
          Out[(size_t)row * N + col] = f2bf(oo * qs);
        }
      }
    }
  } else {
#pragma unroll
    for (int n = 0; n < 4; ++n) {
      const int col = col0 + wn * 64 + n * 16 + cc;
      const float bb = bias[col];
#pragma unroll
      for (int m = 0; m < 4; ++m) {
        const int rw = row0 + wm * 64 + m * 16 + hi * 4;
#pragma unroll
        for (int r = 0; r < 4; ++r)
          Out[(size_t)(rw + r) * N + col] = f2bf(acc[m][n][r] + bb);
      }
    }
  }
}

// ---------------- MFMA causal flash attention: balanced pairing + key-split ----------------
// Block (x, h, bh): q-chunks qtA = x, qtB = 31-x (64 rows each); processes key
// tiles kt = h, h+2, ... (half the keys). ~16.5 tiles/block, 1024 equal blocks
// -> 4 blocks/CU (16 waves). Stores PARTIAL (O fp32, m, l); merge kernel combines.
__global__ __launch_bounds__(256, 4) void flash_mfma(
    const u16* __restrict__ Qb, const u16* __restrict__ Kb,
    const u16* __restrict__ Vb, float* __restrict__ Opart,
    float2* __restrict__ Mpart) {
  const int T = 2048, C = 1024;
  __shared__ __attribute__((aligned(16))) u16 Ks[2][64 * 64];   // swizzled [key][d]
  __shared__ __attribute__((aligned(16))) u16 Vt[2][64 * 64];   // swizzled [d][key]
  __shared__ __attribute__((aligned(16))) u16 Ps[4][16 * 64];   // per-wave P[q][key]

  const int tid = threadIdx.x;
  const int lane = tid & 63;
  const int hi = lane >> 4, cc = lane & 15;
  const int hi4 = hi * 4;
  const int w = tid >> 6;
  const int qtA = blockIdx.x;        // 0..15
  const int qtB = 31 - qtA;          // 16..31
  const int h = blockIdx.y;          // key half: tiles h, h+2, ...
  const int bh = blockIdx.z;
  const size_t hbase = (size_t)(bh >> 4) * T * C + (size_t)(bh & 15) * 64;
  const int qA0w = qtA * 64 + w * 16;
  const int qB0w = qtB * 64 + w * 16;

  // Q fragments (B-operand of swapped QK^T; Q pre-scaled by QSCALE)
  short8 qaA0, qaA1, qaB0, qaB1;
  {
    const u16* qp = Qb + hbase + (size_t)(qA0w + cc) * C + hi * 8;
    qaA0 = *(const short8*)qp;
    qaA1 = *(const short8*)(qp + 32);
    qp = Qb + hbase + (size_t)(qB0w + cc) * C + hi * 8;
    qaB0 = *(const short8*)qp;
    qaB1 = *(const short8*)(qp + 32);
  }

  f32x4 oA[4], oB[4];
#pragma unroll
  for (int nt = 0; nt < 4; ++nt) {
    oA[nt] = f32x4{0.f, 0.f, 0.f, 0.f};
    oB[nt] = f32x4{0.f, 0.f, 0.f, 0.f};
  }
  float mA = -1e30f, lA = 0.f, mB = -1e30f, lB = 0.f;

  // staging maps (block-cooperative)
  const int krow = tid >> 2, kcol = (tid & 3) * 16;
  const int vd0 = (tid & 31) * 2, vkey0 = (tid >> 5) * 8;
  const u16* kgp = Kb + hbase + (size_t)krow * C + kcol;
  const u16* vgp = Vb + hbase + (size_t)vkey0 * C + vd0;

  short8 kr0, kr1;
  u32 vr_[8];

  auto LOADT = [&](int kt) {
    const size_t off = (size_t)(kt * 64) * C;
    kr0 = *(const short8*)(kgp + off);
    kr1 = *(const short8*)(kgp + off + 8);
#pragma unroll
    for (int j = 0; j < 8; ++j)
      vr_[j] = *(const u32*)(vgp + off + (size_t)j * C);
  };

  char* PsB = (char*)(Ps[w]);
  char* KsCur;
  char* VtCur;

  auto WRITET = [&](int buf) {
    char* KsB = (char*)(Ks[buf]);
    char* VtB = (char*)(Vt[buf]);
    const int kb = krow * 128 + kcol * 2;
    const int ksw = (krow & 7) << 4;
    *(short8*)(KsB + (kb ^ ksw)) = kr0;
    *(short8*)(KsB + ((kb + 16) ^ ksw)) = kr1;
    u32 lo0 = (vr_[0] & 0xFFFFu) | (vr_[1] << 16);
    u32 lo1 = (vr_[2] & 0xFFFFu) | (vr_[3] << 16);
    u32 lo2 = (vr_[4] & 0xFFFFu) | (vr_[5] << 16);
    u32 lo3 = (vr_[6] & 0xFFFFu) | (vr_[7] << 16);
    u32 hh0 = (vr_[0] >> 16) | (vr_[1] & 0xFFFF0000u);
    u32 hh1 = (vr_[2] >> 16) | (vr_[3] & 0xFFFF0000u);
    u32 hh2 = (vr_[4] >> 16) | (vr_[5] & 0xFFFF0000u);
    u32 hh3 = (vr_[6] >> 16) | (vr_[7] & 0xFFFF0000u);
    const int d1 = vd0 + 1;
    u32x4 vlo = {lo0, lo1, lo2, lo3};
    u32x4 vhi = {hh0, hh1, hh2, hh3};
    *(u32x4*)(VtB + ((vd0 * 128 + vkey0 * 2) ^ ((vd0 & 7) << 4))) = vlo;
    *(u32x4*)(VtB + ((d1 * 128 + vkey0 * 2) ^ ((d1 & 7) << 4))) = vhi;
  };

  const int ksw2 = (cc & 7) << 4;
  short8 kf[4][2];

  // one chunk's QK^T -> softmax -> P stage -> PV
  auto CHUNK = [&](const short8& qa0, const short8& qa1, f32x4* o,
                   float& mrow, float& lsum, bool diag) {
    f32x4 s[4];
#pragma unroll
    for (int nt = 0; nt < 4; ++nt) {
      f32x4 z = f32x4{0.f, 0.f, 0.f, 0.f};
      z = MFMA32(kf[nt][0], qa0, z);
      z = MFMA32(kf[nt][1], qa1, z);
      s[nt] = z;
    }
    if (diag) {
      const int qloc = w * 16 + cc;
#pragma unroll
      for (int nt = 0; nt < 4; ++nt)
#pragma unroll
        for (int r = 0; r < 4; ++r)
          if (nt * 16 + hi4 + r > qloc) s[nt][r] = -1e30f;
    }
    float tm = s[0][0];
#pragma unroll
    for (int nt = 0; nt < 4; ++nt)
#pragma unroll
      for (int r = 0; r < 4; ++r) tm = fmaxf(tm, s[nt][r]);
    tm = fmaxf(tm, __shfl_xor(tm, 16));
    tm = fmaxf(tm, __shfl_xor(tm, 32));

    const bool need = tm > mrow + 8.0f;      // defer-max
    float corr = 1.0f;
    if (need) { corr = exp2f(mrow - tm); mrow = tm; }

    float psum = 0.f;
#pragma unroll
    for (int nt = 0; nt < 4; ++nt) {
      float e0 = exp2f(s[nt][0] - mrow);
      float e1 = exp2f(s[nt][1] - mrow);
      float e2 = exp2f(s[nt][2] - mrow);
      float e3 = exp2f(s[nt][3] - mrow);
      psum += (e0 + e1) + (e2 + e3);
      u32 pr[2] = { pk_bf16(e0, e1), pk_bf16(e2, e3) };
      *(u64*)(PsB + ((cc * 128 + nt * 32 + hi * 8) ^ ksw2)) = *(const u64*)pr;
    }
    psum += __shfl_xor(psum, 16);
    psum += __shfl_xor(psum, 32);
    lsum = lsum * corr + psum;
    if (__any(need)) {
#pragma unroll
      for (int nt = 0; nt < 4; ++nt) o[nt] *= corr;
    }

#pragma unroll
    for (int kc = 0; kc < 2; ++kc) {
      short8 pa = *(const short8*)(PsB + ((cc * 128 + kc * 64 + hi * 16) ^ ksw2));
#pragma unroll
      for (int nt = 0; nt < 4; ++nt) {
        short8 vb = *(const short8*)(VtCur + (((nt * 16 + cc) * 128 + kc * 64 + hi * 16) ^ ksw2));
        o[nt] = MFMA32(vb, pa, o[nt]);
      }
    }
  };

  // prologue: stage first assigned tile into buf0, prefetch next into regs
  LOADT(h);
  WRITET(0);
  if (h + 2 <= qtB) LOADT(h + 2);
  __syncthreads();

  int idx = 0;
  for (int kt = h; kt <= qtB; kt += 2, ++idx) {
    const int cur = idx & 1;
    const bool more = (kt + 2 <= qtB);
    if (more) {
      WRITET(cur ^ 1);                       // stage tile kt+2 into other buf
      if (kt + 4 <= qtB) LOADT(kt + 4);      // prefetch tile kt+4 into regs
    }
    KsCur = (char*)(Ks[cur]);
    VtCur = (char*)(Vt[cur]);

    // K fragments (A-operand), shared by both chunks
#pragma unroll
    for (int nt = 0; nt < 4; ++nt) {
      const int kb = (nt * 16 + cc) * 128 + hi * 16;
      kf[nt][0] = *(const short8*)(KsCur + (kb ^ ksw2));
      kf[nt][1] = *(const short8*)(KsCur + ((kb + 64) ^ ksw2));
    }

    CHUNK(qaB0, qaB1, oB, mB, lB, kt == qtB);
    if (kt <= qtA) CHUNK(qaA0, qaA1, oA, mA, lA, kt == qtA);

    if (more) __syncthreads();               // staged tile kt+2 visible
  }

  // partial epilogue: raw O (fp32), m, l  — no normalization here
  float* Op = Opart + ((size_t)h * 65536 + (size_t)bh * 2048) * 64;
#pragma unroll
  for (int nt = 0; nt < 4; ++nt) {
    *(f32x4*)(Op + (size_t)(qA0w + cc) * 64 + nt * 16 + hi4) = oA[nt];
    *(f32x4*)(Op + (size_t)(qB0w + cc) * 64 + nt * 16 + hi4) = oB[nt];
  }
  if (hi == 0) {
    float2* Ml = Mpart + (size_t)h * 65536 + (size_t)bh * 2048;
    Ml[qA0w + cc] = make_float2(mA, lA);
    Ml[qB0w + cc] = make_float2(mB, lB);
  }
}

// ---------------- merge two key-halves -> Y (bf16) ----------------
__global__ void flash_merge(const float* __restrict__ Opart,
                            const float2* __restrict__ Mpart,
                            u16* __restrict__ Yb) {
  const int i = blockIdx.x * 256 + threadIdx.x;   // 524288 threads
  const int row = i >> 3;                         // bh*2048 + q
  const int d0 = (i & 7) * 8;
  const float2 a = Mpart[row];
  const float2 b = Mpart[65536 + row];
  const float m = fmaxf(a.x, b.x);
  const float wA = exp2f(a.x - m), wB = exp2f(b.x - m);
  const float inv = 1.0f / (a.y * wA + b.y * wB);
  const float* oA = Opart + (size_t)row * 64 + d0;
  const float* oB = Opart + (size_t)(65536 + row) * 64 + d0;
  f32x4 a0 = *(const f32x4*)oA;
  f32x4 a1 = *(const f32x4*)(oA + 4);
  f32x4 b0 = *(const f32x4*)oB;
  f32x4 b1 = *(const f32x4*)(oB + 4);
  u16x8 y;
#pragma unroll
  for (int r = 0; r < 4; ++r) {
    y[r]     = f2bf((a0[r] * wA + b0[r] * wB) * inv);
    y[r + 4] = f2bf((a1[r] * wA + b1[r] * wB) * inv);
  }
  const int bh = row >> 11, q = row & 2047;
  u16* dst = Yb + (size_t)(bh >> 4) * 2048 * 1024 + (size_t)q * 1024 + (bh & 15) * 64 + d0;
  *(u16x8*)dst = y;
}

// ---------------- proj GEMM: BN=64, fp32 out ----------------
__global__ __launch_bounds__(256, 2) void gemm_proj(
    const u16* __restrict__ A, const u16* __restrict__ W,
    const float* __restrict__ bias, float* __restrict__ Out) {
  const int K = 1024, N = 1024;
  __shared__ __attribute__((aligned(16))) u16 As[128 * 32];
  __shared__ __attribute__((aligned(16))) u16 Bs[64 * 32];
  const int tid = threadIdx.x;
  const int lane = tid & 63;
  const int hi = lane >> 4, cc = lane & 15;
  const int w = tid >> 6, wm = w >> 1, wn = w & 1;
  const int row0 = blockIdx.y * 128, col0 = blockIdx.x * 64;

  const int lr = tid >> 2;
  const int lk = (tid & 3) * 8;
  const u16* Ag0 = A + (size_t)(row0 + lr) * K + lk;
  const u16* Ag1 = A + (size_t)(row0 + 64 + lr) * K + lk;
  const u16* Wg0 = W + (size_t)(col0 + lr) * K + lk;
  u16* Al0 = As + tid * 8;
  u16* Al1 = As + 2048 + tid * 8;
  u16* Bl0 = Bs + tid * 8;

  f32x4 acc[4][2];
#pragma unroll
  for (int m = 0; m < 4; ++m)
#pragma unroll
    for (int n = 0; n < 2; ++n) acc[m][n] = f32x4{0.f, 0.f, 0.f, 0.f};

  for (int k0 = 0; k0 < K; k0 += 32) {
    __syncthreads();
    gl_lds16(Ag0 + k0, Al0);
    gl_lds16(Ag1 + k0, Al1);
    gl_lds16(Wg0 + k0, Bl0);
    __syncthreads();
    short8 a[4], b[2];
#pragma unroll
    for (int m = 0; m < 4; ++m)
      a[m] = *(const short8*)(As + (wm * 64 + m * 16 + cc) * 32 + hi * 8);
#pragma unroll
    for (int n = 0; n < 2; ++n)
      b[n] = *(const short8*)(Bs + (wn * 32 + n * 16 + cc) * 32 + hi * 8);
#pragma unroll
    for (int m = 0; m < 4; ++m)
#pragma unroll
      for (int n = 0; n < 2; ++n)
        acc[m][n] = MFMA32(a[m], b[n], acc[m][n]);
  }

#pragma unroll
  for (int n = 0; n < 2; ++n) {
    const int col = col0 + wn * 32 + n * 16 + cc;
    const float bb = bias[col];
#pragma unroll
    for (int m = 0; m < 4; ++m) {
      const int rw = row0 + wm * 64 + m * 16 + hi * 4;
#pragma unroll
      for (int r = 0; r < 4; ++r)
        Out[(size_t)(rw + r) * N + col] = acc[m][n][r] + bb;
    }
  }
}

extern "C" void kernel_launch(void* const* d_in, const int* in_sizes, int n_in,
                              void* d_out, int out_size, void* d_ws, size_t ws_size,
                              hipStream_t stream) {
  const float* x  = (const float*)d_in[0];
  const float* Wq = (const float*)d_in[1];
  const float* bq = (const float*)d_in[2];
  const float* Wk = (const float*)d_in[3];
  const float* bk = (const float*)d_in[4];
  const float* Wv = (const float*)d_in[5];
  const float* bv = (const float*)d_in[6];
  const float* Wp = (const float*)d_in[7];
  const float* bp = (const float*)d_in[8];
  float* out = (float*)d_out;

  const int B = 2, T = 2048, C = 1024;
  const int M = B * T;
  const size_t MC = (size_t)M * C;
  const size_t CC = (size_t)C * C;

  char* p = (char*)d_ws;
  u16* xb  = (u16*)p;  p += MC * 2;    // reused as Y after QKV GEMM
  u16* Wqb = (u16*)p;  p += CC * 2;
  u16* Wkb = (u16*)p;  p += CC * 2;
  u16* Wvb = (u16*)p;  p += CC * 2;
  u16* Wpb = (u16*)p;  p += CC * 2;
  u16* Qbb = (u16*)p;  p += MC * 2;
  u16* Kbb = (u16*)p;  p += MC * 2;
  u16* Vbb = (u16*)p;  p += MC * 2;
  float* cosT = (float*)p; p += (size_t)T * 32 * 4;
  float* sinT = (float*)p; p += (size_t)T * 32 * 4;
  float* Opart = (float*)p; p += (size_t)2 * 65536 * 64 * 4;   // 33.6 MB
  float2* Mpart = (float2*)p; p += (size_t)2 * 65536 * 8;

  rope_table<<<T * 32 / 256, 256, 0, stream>>>(cosT, sinT, T);
  const int n4x = (int)(MC / 4);
  const int n4tot = n4x + 4 * (int)(CC / 4);
  cvt_all<<<n4tot / 256, 256, 0, stream>>>(x, Wq, Wk, Wv, Wp, xb, Wqb, Wkb, Wvb, Wpb, n4x);

  dim3 gq(24, M / 128);
  gemm_qkv<<<gq, 256, 0, stream>>>(xb, Wqb, Wkb, Wvb, bq, bk, bv, cosT, sinT, Qbb, Kbb, Vbb);

  dim3 fg(16, 2, B * 16);
  flash_mfma<<<fg, 256, 0, stream>>>(Qbb, Kbb, Vbb, Opart, Mpart);

  flash_merge<<<524288 / 256, 256, 0, stream>>>(Opart, Mpart, xb);  // Y -> xb

  dim3 gp(C / 64, M / 128);
  gemm_proj<<<gp, 256, 0, stream>>>(xb, Wpb, bp, out);
}

// Round 12
// 128.129 us; speedup vs baseline: 1.3745x; 1.3745x over previous
//
#include <hip/hip_runtime.h>
#include <math.h>

typedef unsigned short u16;
typedef unsigned int u32;
typedef unsigned long long u64;
typedef __attribute__((ext_vector_type(8))) short short8;
typedef __attribute__((ext_vector_type(4))) float f32x4;
typedef __attribute__((ext_vector_type(4))) u16 u16x4;
typedef __attribute__((ext_vector_type(4))) u32 u32x4;

#define AS1 __attribute__((address_space(1)))
#define AS3 __attribute__((address_space(3)))

// 0.125 * log2(e): QK^T scores scaled so softmax = exp2
#define QSCALE 0.18033688011112042f

__device__ __forceinline__ u16 f2bf(float f) {
  union { float f; u32 i; } u; u.f = f;
  u32 r = u.i + 0x7FFFu + ((u.i >> 16) & 1u);
  return (u16)(r >> 16);
}

__device__ __forceinline__ u32 pk_bf16(float a, float b) {
  u32 r;
  asm volatile("v_cvt_pk_bf16_f32 %0, %1, %2" : "=v"(r) : "v"(a), "v"(b));
  return r;
}

__device__ __forceinline__ void gl_lds16(const void* g, void* l) {
  __builtin_amdgcn_global_load_lds((const AS1 u32*)g, (AS3 u32*)l, 16, 0, 0);
}

#define MFMA32(a, b, c) __builtin_amdgcn_mfma_f32_16x16x32_bf16(a, b, c, 0, 0, 0)

// ---------------- fused convert (x + 4 weights) + RoPE table ----------------
__global__ void cvt_all(const float* __restrict__ x,
                        const float* __restrict__ Wq, const float* __restrict__ Wk,
                        const float* __restrict__ Wv, const float* __restrict__ Wp,
                        u16* __restrict__ xb,
                        u16* __restrict__ Wqb, u16* __restrict__ Wkb,
                        u16* __restrict__ Wvb, u16* __restrict__ Wpb,
                        float* __restrict__ cosT, float* __restrict__ sinT,
                        int n4x, int n4tot) {
  int i = blockIdx.x * 256 + threadIdx.x;
  if (i >= n4tot) {                    // RoPE table tail: 65536 items
    int k = i - n4tot;
    int t = k >> 5, j = k & 31;
    float inv = powf(10000.0f, -(float)j / 32.0f);
    float ang = (float)t * inv;
    cosT[k] = cosf(ang);
    sinT[k] = sinf(ang);
    return;
  }
  const float* src; u16* dst; int off;
  if (i < n4x) { src = x; dst = xb; off = i; }
  else {
    int wi = i - n4x;
    int sel = wi >> 18;                // CC/4 = 2^18
    off = wi & ((1 << 18) - 1);
    src = sel == 0 ? Wq : sel == 1 ? Wk : sel == 2 ? Wv : Wp;
    dst = sel == 0 ? Wqb : sel == 1 ? Wkb : sel == 2 ? Wvb : Wpb;
  }
  float4 v = ((const float4*)src)[off];
  u16x4 o = { f2bf(v.x), f2bf(v.y), f2bf(v.z), f2bf(v.w) };
  ((u16x4*)dst)[off] = o;
}

// ---------------- fused QKV GEMM (bf16 MFMA) with RoPE epilogue ----------------
// LDS staging swizzled: gl_lds linear dest + pre-swizzled global source
// (block = (tid&3) ^ (row&3)); frag reads XOR'd (block = hi ^ (cc&3)).
__global__ __launch_bounds__(256, 2) void gemm_qkv(
    const u16* __restrict__ xb,
    const u16* __restrict__ Wqb, const u16* __restrict__ Wkb, const u16* __restrict__ Wvb,
    const float* __restrict__ bq, const float* __restrict__ bk, const float* __restrict__ bv,
    const float* __restrict__ cosT, const float* __restrict__ sinT,
    u16* __restrict__ Qb, u16* __restrict__ Kb, u16* __restrict__ Vb) {
  const int K = 1024, N = 1024;
  __shared__ __attribute__((aligned(16))) u16 As[128 * 32];
  __shared__ __attribute__((aligned(16))) u16 Bs[128 * 32];
  const int tid = threadIdx.x;
  const int lane = tid & 63;
  const int hi = lane >> 4, cc = lane & 15;
  const int w = tid >> 6, wm = w >> 1, wn = w & 1;
  const int sel = blockIdx.x >> 3;
  const int row0 = blockIdx.y * 128, col0 = (blockIdx.x & 7) * 128;
  const u16* W = sel == 0 ? Wqb : sel == 1 ? Wkb : Wvb;
  const float* bias = sel == 0 ? bq : sel == 1 ? bk : bv;
  u16* Out = sel == 0 ? Qb : sel == 1 ? Kb : Vb;

  const int lr = tid >> 2;                                  // row 0..63
  const int lk = (((tid & 3) ^ (lr & 3)) * 8);              // pre-swizzled src block
  const u16* Ag0 = xb + (size_t)(row0 + lr) * K + lk;
  const u16* Ag1 = xb + (size_t)(row0 + 64 + lr) * K + lk;  // (64+lr)&3 == lr&3
  const u16* Wg0 = W + (size_t)(col0 + lr) * K + lk;
  const u16* Wg1 = W + (size_t)(col0 + 64 + lr) * K + lk;
  u16* Al0 = As + tid * 8;
  u16* Al1 = As + 2048 + tid * 8;
  u16* Bl0 = Bs + tid * 8;
  u16* Bl1 = Bs + 2048 + tid * 8;

  const int rb = (hi ^ (cc & 3)) * 8;                       // swizzled read block

  f32x4 acc[4][4];
#pragma unroll
  for (int m = 0; m < 4; ++m)
#pragma unroll
    for (int n = 0; n < 4; ++n) acc[m][n] = f32x4{0.f, 0.f, 0.f, 0.f};

  for (int k0 = 0; k0 < K; k0 += 32) {
    __syncthreads();
    gl_lds16(Ag0 + k0, Al0);
    gl_lds16(Ag1 + k0, Al1);
    gl_lds16(Wg0 + k0, Bl0);
    gl_lds16(Wg1 + k0, Bl1);
    __syncthreads();
    short8 a[4], b[4];
#pragma unroll
    for (int m = 0; m < 4; ++m)
      a[m] = *(const short8*)(As + (wm * 64 + m * 16 + cc) * 32 + rb);
#pragma unroll
    for (int n = 0; n < 4; ++n)
      b[n] = *(const short8*)(Bs + (wn * 64 + n * 16 + cc) * 32 + rb);
#pragma unroll
    for (int m = 0; m < 4; ++m)
#pragma unroll
      for (int n = 0; n < 4; ++n)
        acc[m][n] = MFMA32(a[m], b[n], acc[m][n]);
  }

  if (sel < 2) {
    const float qs = (sel == 0) ? QSCALE : 1.0f;
#pragma unroll
    for (int n = 0; n < 4; ++n) {
      const int col = col0 + wn * 64 + n * 16 + cc;
      const int j = (col & 63) >> 1;
      const float bb = bias[col];
#pragma unroll
      for (int m = 0; m < 4; ++m) {
        const int rw = row0 + wm * 64 + m * 16 + hi * 4;
#pragma unroll
        for (int r = 0; r < 4; ++r) {
          const int row = rw + r;
          const int t = row & 2047;
          float v = acc[m][n][r] + bb;
          float pv = __shfl_xor(v, 1);
          float c = cosT[t * 32 + j], s = sinT[t * 32 + j];
          float oo = (cc & 1) ? (s * pv + c * v) : (c * v - s * pv);
          Out[(size_t)row * N + col] = f2bf(oo * qs);
        }
      }
    }
  } else {
#pragma unroll
    for (int n = 0; n < 4; ++n) {
      const int col = col0 + wn * 64 + n * 16 + cc;
      const float bb = bias[col];
#pragma unroll
      for (int m = 0; m < 4; ++m) {
        const int rw = row0 + wm * 64 + m * 16 + hi * 4;
#pragma unroll
        for (int r = 0; r < 4; ++r)
          Out[(size_t)(rw + r) * N + col] = f2bf(acc[m][n][r] + bb);
      }
    }
  }
}

// ---------------- MFMA causal flash attention, balanced pairing (R9, proven) ----------------
__global__ __launch_bounds__(256, 2) void flash_mfma(
    const u16* __restrict__ Qb, const u16* __restrict__ Kb,
    const u16* __restrict__ Vb, u16* __restrict__ Yb) {
  const int T = 2048, C = 1024;
  __shared__ __attribute__((aligned(16))) u16 Ks[64 * 64];      // swizzled [key][d]
  __shared__ __attribute__((aligned(16))) u16 Vt[64 * 64];      // swizzled [d][key]
  __shared__ __attribute__((aligned(16))) u16 Ps[4][16 * 64];   // per-wave P[q][key]

  const int tid = threadIdx.x;
  const int lane = tid & 63;
  const int hi = lane >> 4, cc = lane & 15;
  const int hi4 = hi * 4;
  const int w = tid >> 6;
  const int qtA = blockIdx.x;        // 0..15
  const int qtB = 31 - qtA;          // 16..31
  const int bh = blockIdx.y;
  const size_t hbase = (size_t)(bh >> 4) * T * C + (size_t)(bh & 15) * 64;
  const int qA0w = qtA * 64 + w * 16;
  const int qB0w = qtB * 64 + w * 16;

  short8 qaA0, qaA1, qaB0, qaB1;
  {
    const u16* qp = Qb + hbase + (size_t)(qA0w + cc) * C + hi * 8;
    qaA0 = *(const short8*)qp;
    qaA1 = *(const short8*)(qp + 32);
    qp = Qb + hbase + (size_t)(qB0w + cc) * C + hi * 8;
    qaB0 = *(const short8*)qp;
    qaB1 = *(const short8*)(qp + 32);
  }

  f32x4 oA[4], oB[4];
#pragma unroll
  for (int nt = 0; nt < 4; ++nt) {
    oA[nt] = f32x4{0.f, 0.f, 0.f, 0.f};
    oB[nt] = f32x4{0.f, 0.f, 0.f, 0.f};
  }
  float mA = -1e30f, lA = 0.f, mB = -1e30f, lB = 0.f;

  const int krow = tid >> 2, kcol = (tid & 3) * 16;
  const int vd0 = (tid & 31) * 2, vkey0 = (tid >> 5) * 8;
  const u16* kgp = Kb + hbase + (size_t)krow * C + kcol;
  const u16* vgp = Vb + hbase + (size_t)vkey0 * C + vd0;

  short8 kr0, kr1;
  u32 vr_[8];

  auto LOADT = [&](int kt) {
    const size_t off = (size_t)(kt * 64) * C;
    kr0 = *(const short8*)(kgp + off);
    kr1 = *(const short8*)(kgp + off + 8);
#pragma unroll
    for (int j = 0; j < 8; ++j)
      vr_[j] = *(const u32*)(vgp + off + (size_t)j * C);
  };

  char* KsB = (char*)Ks;
  char* VtB = (char*)Vt;
  char* PsB = (char*)(Ps[w]);

  auto WRITET = [&]() {
    const int kb = krow * 128 + kcol * 2;
    const int ksw = (krow & 7) << 4;
    *(short8*)(KsB + (kb ^ ksw)) = kr0;
    *(short8*)(KsB + ((kb + 16) ^ ksw)) = kr1;
    u32 lo0 = (vr_[0] & 0xFFFFu) | (vr_[1] << 16);
    u32 lo1 = (vr_[2] & 0xFFFFu) | (vr_[3] << 16);
    u32 lo2 = (vr_[4] & 0xFFFFu) | (vr_[5] << 16);
    u32 lo3 = (vr_[6] & 0xFFFFu) | (vr_[7] << 16);
    u32 hh0 = (vr_[0] >> 16) | (vr_[1] & 0xFFFF0000u);
    u32 hh1 = (vr_[2] >> 16) | (vr_[3] & 0xFFFF0000u);
    u32 hh2 = (vr_[4] >> 16) | (vr_[5] & 0xFFFF0000u);
    u32 hh3 = (vr_[6] >> 16) | (vr_[7] & 0xFFFF0000u);
    const int d1 = vd0 + 1;
    u32x4 vlo = {lo0, lo1, lo2, lo3};
    u32x4 vhi = {hh0, hh1, hh2, hh3};
    *(u32x4*)(VtB + ((vd0 * 128 + vkey0 * 2) ^ ((vd0 & 7) << 4))) = vlo;
    *(u32x4*)(VtB + ((d1 * 128 + vkey0 * 2) ^ ((d1 & 7) << 4))) = vhi;
  };

  const int ksw2 = (cc & 7) << 4;
  short8 kf[4][2];

  auto CHUNK = [&](const short8& qa0, const short8& qa1, f32x4* o,
                   float& mrow, float& lsum, bool diag) {
    f32x4 s[4];
#pragma unroll
    for (int nt = 0; nt < 4; ++nt) {
      f32x4 z = f32x4{0.f, 0.f, 0.f, 0.f};
      z = MFMA32(kf[nt][0], qa0, z);
      z = MFMA32(kf[nt][1], qa1, z);
      s[nt] = z;
    }
    if (diag) {
      const int qloc = w * 16 + cc;
#pragma unroll
      for (int nt = 0; nt < 4; ++nt)
#pragma unroll
        for (int r = 0; r < 4; ++r)
          if (nt * 16 + hi4 + r > qloc) s[nt][r] = -1e30f;
    }
    float tm = s[0][0];
#pragma unroll
    for (int nt = 0; nt < 4; ++nt)
#pragma unroll
      for (int r = 0; r < 4; ++r) tm = fmaxf(tm, s[nt][r]);
    tm = fmaxf(tm, __shfl_xor(tm, 16));
    tm = fmaxf(tm, __shfl_xor(tm, 32));

    const bool need = tm > mrow + 8.0f;      // defer-max
    float corr = 1.0f;
    if (need) { corr = exp2f(mrow - tm); mrow = tm; }

    float psum = 0.f;
#pragma unroll
    for (int nt = 0; nt < 4; ++nt) {
      float e0 = exp2f(s[nt][0] - mrow);
      float e1 = exp2f(s[nt][1] - mrow);
      float e2 = exp2f(s[nt][2] - mrow);
      float e3 = exp2f(s[nt][3] - mrow);
      psum += (e0 + e1) + (e2 + e3);
      u32 pr[2] = { pk_bf16(e0, e1), pk_bf16(e2, e3) };
      *(u64*)(PsB + ((cc * 128 + nt * 32 + hi * 8) ^ ksw2)) = *(const u64*)pr;
    }
    psum += __shfl_xor(psum, 16);
    psum += __shfl_xor(psum, 32);
    lsum = lsum * corr + psum;
    if (__any(need)) {
#pragma unroll
      for (int nt = 0; nt < 4; ++nt) o[nt] *= corr;
    }

#pragma unroll
    for (int kc = 0; kc < 2; ++kc) {
      short8 pa = *(const short8*)(PsB + ((cc * 128 + kc * 64 + hi * 16) ^ ksw2));
#pragma unroll
      for (int nt = 0; nt < 4; ++nt) {
        short8 vb = *(const short8*)(VtB + (((nt * 16 + cc) * 128 + kc * 64 + hi * 16) ^ ksw2));
        o[nt] = MFMA32(vb, pa, o[nt]);
      }
    }
  };

  // prologue: stage tile 0, prefetch tile 1
  LOADT(0);
  WRITET();
  LOADT(1);                       // qtB >= 16, always more than 1 tile
  __syncthreads();

  for (int kt = 0; kt <= qtB; ++kt) {
#pragma unroll
    for (int nt = 0; nt < 4; ++nt) {
      const int kb = (nt * 16 + cc) * 128 + hi * 16;
      kf[nt][0] = *(const short8*)(KsB + (kb ^ ksw2));
      kf[nt][1] = *(const short8*)(KsB + ((kb + 64) ^ ksw2));
    }

    CHUNK(qaB0, qaB1, oB, mB, lB, kt == qtB);
    if (kt <= qtA) CHUNK(qaA0, qaA1, oA, mA, lA, kt == qtA);

    if (kt < qtB) {
      __syncthreads();             // all waves done reading Ks/Vt
      WRITET();                    // stage tile kt+1 (regs from last LOADT)
      if (kt + 1 < qtB) LOADT(kt + 2);   // prefetch tile kt+2
      __syncthreads();             // staged tile visible
    }
  }

  const float ivA = 1.0f / lA, ivB = 1.0f / lB;
#pragma unroll
  for (int nt = 0; nt < 4; ++nt) {
    u16x4 yA = { f2bf(oA[nt][0] * ivA), f2bf(oA[nt][1] * ivA),
                 f2bf(oA[nt][2] * ivA), f2bf(oA[nt][3] * ivA) };
    *(u16x4*)(Yb + hbase + (size_t)(qA0w + cc) * C + nt * 16 + hi4) = yA;
    u16x4 yB = { f2bf(oB[nt][0] * ivB), f2bf(oB[nt][1] * ivB),
                 f2bf(oB[nt][2] * ivB), f2bf(oB[nt][3] * ivB) };
    *(u16x4*)(Yb + hbase + (size_t)(qB0w + cc) * C + nt * 16 + hi4) = yB;
  }
}

// ---------------- proj GEMM: BN=64, fp32 out, swizzled LDS ----------------
__global__ __launch_bounds__(256, 2) void gemm_proj(
    const u16* __restrict__ A, const u16* __restrict__ W,
    const float* __restrict__ bias, float* __restrict__ Out) {
  const int K = 1024, N = 1024;
  __shared__ __attribute__((aligned(16))) u16 As[128 * 32];
  __shared__ __attribute__((aligned(16))) u16 Bs[64 * 32];
  const int tid = threadIdx.x;
  const int lane = tid & 63;
  const int hi = lane >> 4, cc = lane & 15;
  const int w = tid >> 6, wm = w >> 1, wn = w & 1;
  const int row0 = blockIdx.y * 128, col0 = blockIdx.x * 64;

  const int lr = tid >> 2;
  const int lk = (((tid & 3) ^ (lr & 3)) * 8);              // pre-swizzled src block
  const u16* Ag0 = A + (size_t)(row0 + lr) * K + lk;
  const u16* Ag1 = A + (size_t)(row0 + 64 + lr) * K + lk;
  const u16* Wg0 = W + (size_t)(col0 + lr) * K + lk;
  u16* Al0 = As + tid * 8;
  u16* Al1 = As + 2048 + tid * 8;
  u16* Bl0 = Bs + tid * 8;

  const int rb = (hi ^ (cc & 3)) * 8;                       // swizzled read block

  f32x4 acc[4][2];
#pragma unroll
  for (int m = 0; m < 4; ++m)
#pragma unroll
    for (int n = 0; n < 2; ++n) acc[m][n] = f32x4{0.f, 0.f, 0.f, 0.f};

  for (int k0 = 0; k0 < K; k0 += 32) {
    __syncthreads();
    gl_lds16(Ag0 + k0, Al0);
    gl_lds16(Ag1 + k0, Al1);
    gl_lds16(Wg0 + k0, Bl0);
    __syncthreads();
    short8 a[4], b[2];
#pragma unroll
    for (int m = 0; m < 4; ++m)
      a[m] = *(const short8*)(As + (wm * 64 + m * 16 + cc) * 32 + rb);
#pragma unroll
    for (int n = 0; n < 2; ++n)
      b[n] = *(const short8*)(Bs + (wn * 32 + n * 16 + cc) * 32 + rb);
#pragma unroll
    for (int m = 0; m < 4; ++m)
#pragma unroll
      for (int n = 0; n < 2; ++n)
        acc[m][n] = MFMA32(a[m], b[n], acc[m][n]);
  }

#pragma unroll
  for (int n = 0; n < 2; ++n) {
    const int col = col0 + wn * 32 + n * 16 + cc;
    const float bb = bias[col];
#pragma unroll
    for (int m = 0; m < 4; ++m) {
      const int rw = row0 + wm * 64 + m * 16 + hi * 4;
#pragma unroll
      for (int r = 0; r < 4; ++r)
        Out[(size_t)(rw + r) * N + col] = acc[m][n][r] + bb;
    }
  }
}

extern "C" void kernel_launch(void* const* d_in, const int* in_sizes, int n_in,
                              void* d_out, int out_size, void* d_ws, size_t ws_size,
                              hipStream_t stream) {
  const float* x  = (const float*)d_in[0];
  const float* Wq = (const float*)d_in[1];
  const float* bq = (const float*)d_in[2];
  const float* Wk = (const float*)d_in[3];
  const float* bk = (const float*)d_in[4];
  const float* Wv = (const float*)d_in[5];
  const float* bv = (const float*)d_in[6];
  const float* Wp = (const float*)d_in[7];
  const float* bp = (const float*)d_in[8];
  float* out = (float*)d_out;

  const int B = 2, T = 2048, C = 1024;
  const int M = B * T;
  const size_t MC = (size_t)M * C;
  const size_t CC = (size_t)C * C;

  char* p = (char*)d_ws;
  u16* xb  = (u16*)p;  p += MC * 2;    // reused as Y after QKV GEMM
  u16* Wqb = (u16*)p;  p += CC * 2;
  u16* Wkb = (u16*)p;  p += CC * 2;
  u16* Wvb = (u16*)p;  p += CC * 2;
  u16* Wpb = (u16*)p;  p += CC * 2;
  u16* Qbb = (u16*)p;  p += MC * 2;
  u16* Kbb = (u16*)p;  p += MC * 2;
  u16* Vbb = (u16*)p;  p += MC * 2;
  float* cosT = (float*)p; p += (size_t)T * 32 * 4;
  float* sinT = (float*)p; p += (size_t)T * 32 * 4;

  const int n4x = (int)(MC / 4);
  const int n4tot = n4x + 4 * (int)(CC / 4);
  const int ntot = n4tot + T * 32;     // + RoPE table items
  cvt_all<<<(ntot + 255) / 256, 256, 0, stream>>>(x, Wq, Wk, Wv, Wp,
                                                  xb, Wqb, Wkb, Wvb, Wpb,
                                                  cosT, sinT, n4x, n4tot);

  dim3 gq(24, M / 128);
  gemm_qkv<<<gq, 256, 0, stream>>>(xb, Wqb, Wkb, Wvb, bq, bk, bv, cosT, sinT, Qbb, Kbb, Vbb);

  dim3 fg(16, B * 16);
  flash_mfma<<<fg, 256, 0, stream>>>(Qbb, Kbb, Vbb, xb);   // Y -> xb (reuse)

  dim3 gp(C / 64, M / 128);
  gemm_proj<<<gp, 256, 0, stream>>>(xb, Wpb, bp, out);
}

// Round 13
// 124.173 us; speedup vs baseline: 1.4183x; 1.0319x over previous
//
#include <hip/hip_runtime.h>
#include <math.h>

typedef unsigned short u16;
typedef unsigned int u32;
typedef unsigned long long u64;
typedef __attribute__((ext_vector_type(8))) short short8;
typedef __attribute__((ext_vector_type(4))) float f32x4;
typedef __attribute__((ext_vector_type(4))) u16 u16x4;
typedef __attribute__((ext_vector_type(4))) u32 u32x4;

#define AS1 __attribute__((address_space(1)))
#define AS3 __attribute__((address_space(3)))

// 0.125 * log2(e): QK^T scores scaled so softmax = exp2
#define QSCALE 0.18033688011112042f

__device__ __forceinline__ u16 f2bf(float f) {
  union { float f; u32 i; } u; u.f = f;
  u32 r = u.i + 0x7FFFu + ((u.i >> 16) & 1u);
  return (u16)(r >> 16);
}

__device__ __forceinline__ u32 pk_bf16(float a, float b) {
  u32 r;
  asm volatile("v_cvt_pk_bf16_f32 %0, %1, %2" : "=v"(r) : "v"(a), "v"(b));
  return r;
}

__device__ __forceinline__ void gl_lds16(const void* g, void* l) {
  __builtin_amdgcn_global_load_lds((const AS1 u32*)g, (AS3 u32*)l, 16, 0, 0);
}

#define MFMA32(a, b, c) __builtin_amdgcn_mfma_f32_16x16x32_bf16(a, b, c, 0, 0, 0)

// ---------------- fused convert (x + 4 weights) + RoPE table ----------------
__global__ void cvt_all(const float* __restrict__ x,
                        const float* __restrict__ Wq, const float* __restrict__ Wk,
                        const float* __restrict__ Wv, const float* __restrict__ Wp,
                        u16* __restrict__ xb,
                        u16* __restrict__ Wqb, u16* __restrict__ Wkb,
                        u16* __restrict__ Wvb, u16* __restrict__ Wpb,
                        float* __restrict__ cosT, float* __restrict__ sinT,
                        int n4x, int n4tot) {
  int i = blockIdx.x * 256 + threadIdx.x;
  if (i >= n4tot) {                    // RoPE table tail: 65536 items
    int k = i - n4tot;
    int t = k >> 5, j = k & 31;
    float inv = powf(10000.0f, -(float)j / 32.0f);
    float ang = (float)t * inv;
    cosT[k] = cosf(ang);
    sinT[k] = sinf(ang);
    return;
  }
  const float* src; u16* dst; int off;
  if (i < n4x) { src = x; dst = xb; off = i; }
  else {
    int wi = i - n4x;
    int sel = wi >> 18;                // CC/4 = 2^18
    off = wi & ((1 << 18) - 1);
    src = sel == 0 ? Wq : sel == 1 ? Wk : sel == 2 ? Wv : Wp;
    dst = sel == 0 ? Wqb : sel == 1 ? Wkb : sel == 2 ? Wvb : Wpb;
  }
  float4 v = ((const float4*)src)[off];
  u16x4 o = { f2bf(v.x), f2bf(v.y), f2bf(v.z), f2bf(v.w) };
  ((u16x4*)dst)[off] = o;
}

// ---------------- fused QKV GEMM (bf16 MFMA), BK=64, with RoPE epilogue ----------------
// LDS [row][64] u16; staging: gl_lds linear dest + 8-way pre-swizzled global
// source (block = (tid&7) ^ (row&7)); frag reads block = (kk*4+hi) ^ (cc&7).
__global__ __launch_bounds__(256, 2) void gemm_qkv(
    const u16* __restrict__ xb,
    const u16* __restrict__ Wqb, const u16* __restrict__ Wkb, const u16* __restrict__ Wvb,
    const float* __restrict__ bq, const float* __restrict__ bk, const float* __restrict__ bv,
    const float* __restrict__ cosT, const float* __restrict__ sinT,
    u16* __restrict__ Qb, u16* __restrict__ Kb, u16* __restrict__ Vb) {
  const int K = 1024, N = 1024;
  __shared__ __attribute__((aligned(16))) u16 As[128 * 64];
  __shared__ __attribute__((aligned(16))) u16 Bs[128 * 64];
  const int tid = threadIdx.x;
  const int lane = tid & 63;
  const int hi = lane >> 4, cc = lane & 15;
  const int w = tid >> 6, wm = w >> 1, wn = w & 1;
  const int sel = blockIdx.x >> 3;
  const int row0 = blockIdx.y * 128, col0 = (blockIdx.x & 7) * 128;
  const u16* W = sel == 0 ? Wqb : sel == 1 ? Wkb : Wvb;
  const float* bias = sel == 0 ? bq : sel == 1 ? bk : bv;
  u16* Out = sel == 0 ? Qb : sel == 1 ? Kb : Vb;

  const int lr = tid >> 3;                                   // 0..31
  const int lkb = (((tid & 7) ^ (lr & 7)) * 8);              // pre-swizzled src col
  const u16* Ag = xb + (size_t)(row0 + lr) * K + lkb;
  const u16* Wg = W + (size_t)(col0 + lr) * K + lkb;

  f32x4 acc[4][4];
#pragma unroll
  for (int m = 0; m < 4; ++m)
#pragma unroll
    for (int n = 0; n < 4; ++n) acc[m][n] = f32x4{0.f, 0.f, 0.f, 0.f};

  for (int k0 = 0; k0 < K; k0 += 64) {
    __syncthreads();
#pragma unroll
    for (int j = 0; j < 4; ++j) {
      gl_lds16(Ag + (size_t)j * 32 * K + k0, As + j * 2048 + tid * 8);
      gl_lds16(Wg + (size_t)j * 32 * K + k0, Bs + j * 2048 + tid * 8);
    }
    __syncthreads();
    short8 a[2][4], b[2][4];
#pragma unroll
    for (int kk = 0; kk < 2; ++kk) {
#pragma unroll
      for (int m = 0; m < 4; ++m)
        a[kk][m] = *(const short8*)(As + (wm * 64 + m * 16 + cc) * 64 +
                                    (((kk * 4 + hi) ^ (cc & 7)) * 8));
#pragma unroll
      for (int n = 0; n < 4; ++n)
        b[kk][n] = *(const short8*)(Bs + (wn * 64 + n * 16 + cc) * 64 +
                                    (((kk * 4 + hi) ^ (cc & 7)) * 8));
    }
#pragma unroll
    for (int kk = 0; kk < 2; ++kk)
#pragma unroll
      for (int m = 0; m < 4; ++m)
#pragma unroll
        for (int n = 0; n < 4; ++n)
          acc[m][n] = MFMA32(a[kk][m], b[kk][n], acc[m][n]);
  }

  if (sel < 2) {
    const float qs = (sel == 0) ? QSCALE : 1.0f;
#pragma unroll
    for (int n = 0; n < 4; ++n) {
      const int col = col0 + wn * 64 + n * 16 + cc;
      const int j = (col & 63) >> 1;
      const float bb = bias[col];
#pragma unroll
      for (int m = 0; m < 4; ++m) {
        const int rw = row0 + wm * 64 + m * 16 + hi * 4;
#pragma unroll
        for (int r = 0; r < 4; ++r) {
          const int row = rw + r;
          const int t = row & 2047;
          float v = acc[m][n][r] + bb;
          float pv = __shfl_xor(v, 1);
          float c = cosT[t * 32 + j], s = sinT[t * 32 + j];
          float oo = (cc & 1) ? (s * pv + c * v) : (c * v - s * pv);
          Out[(size_t)row * N + col] = f2bf(oo * qs);
        }
      }
    }
  } else {
#pragma unroll
    for (int n = 0; n < 4; ++n) {
      const int col = col0 + wn * 64 + n * 16 + cc;
      const float bb = bias[col];
#pragma unroll
      for (int m = 0; m < 4; ++m) {
        const int rw = row0 + wm * 64 + m * 16 + hi * 4;
#pragma unroll
        for (int r = 0; r < 4; ++r)
          Out[(size_t)(rw + r) * N + col] = f2bf(acc[m][n][r] + bb);
      }
    }
  }
}

// ---------------- MFMA causal flash attention: balanced pairing, phase-interleaved ----------------
// Block x: chunks qtA = x, qtB = 31-x. Tile body interleaves the two chunks'
// phases (QKT/QKT/SM/SM/PV/PV) so chunk A's softmax VALU fills chunk B's
// P-write->P-read LDS round-trip; V fragments read once for both chunks.
__global__ __launch_bounds__(256, 2) void flash_mfma(
    const u16* __restrict__ Qb, const u16* __restrict__ Kb,
    const u16* __restrict__ Vb, u16* __restrict__ Yb) {
  const int T = 2048, C = 1024;
  __shared__ __attribute__((aligned(16))) u16 Ks[64 * 64];        // swizzled [key][d]
  __shared__ __attribute__((aligned(16))) u16 Vt[64 * 64];        // swizzled [d][key]
  __shared__ __attribute__((aligned(16))) u16 Ps[4][2][16 * 64];  // [wave][chunk] P[q][key]

  const int tid = threadIdx.x;
  const int lane = tid & 63;
  const int hi = lane >> 4, cc = lane & 15;
  const int hi4 = hi * 4;
  const int w = tid >> 6;
  const int qtA = blockIdx.x;        // 0..15
  const int qtB = 31 - qtA;          // 16..31
  const int bh = blockIdx.y;
  const size_t hbase = (size_t)(bh >> 4) * T * C + (size_t)(bh & 15) * 64;
  const int qA0w = qtA * 64 + w * 16;
  const int qB0w = qtB * 64 + w * 16;

  short8 qaA0, qaA1, qaB0, qaB1;
  {
    const u16* qp = Qb + hbase + (size_t)(qA0w + cc) * C + hi * 8;
    qaA0 = *(const short8*)qp;
    qaA1 = *(const short8*)(qp + 32);
    qp = Qb + hbase + (size_t)(qB0w + cc) * C + hi * 8;
    qaB0 = *(const short8*)qp;
    qaB1 = *(const short8*)(qp + 32);
  }

  f32x4 oA[4], oB[4];
#pragma unroll
  for (int nt = 0; nt < 4; ++nt) {
    oA[nt] = f32x4{0.f, 0.f, 0.f, 0.f};
    oB[nt] = f32x4{0.f, 0.f, 0.f, 0.f};
  }
  float mA = -1e30f, lA = 0.f, mB = -1e30f, lB = 0.f;

  const int krow = tid >> 2, kcol = (tid & 3) * 16;
  const int vd0 = (tid & 31) * 2, vkey0 = (tid >> 5) * 8;
  const u16* kgp = Kb + hbase + (size_t)krow * C + kcol;
  const u16* vgp = Vb + hbase + (size_t)vkey0 * C + vd0;

  short8 kr0, kr1;
  u32 vr_[8];

  auto LOADT = [&](int kt) {
    const size_t off = (size_t)(kt * 64) * C;
    kr0 = *(const short8*)(kgp + off);
    kr1 = *(const short8*)(kgp + off + 8);
#pragma unroll
    for (int j = 0; j < 8; ++j)
      vr_[j] = *(const u32*)(vgp + off + (size_t)j * C);
  };

  char* KsB = (char*)Ks;
  char* VtB = (char*)Vt;
  char* PsA_ = (char*)(Ps[w][0]);
  char* PsB_ = (char*)(Ps[w][1]);

  auto WRITET = [&]() {
    const int kb = krow * 128 + kcol * 2;
    const int ksw = (krow & 7) << 4;
    *(short8*)(KsB + (kb ^ ksw)) = kr0;
    *(short8*)(KsB + ((kb + 16) ^ ksw)) = kr1;
    u32 lo0 = (vr_[0] & 0xFFFFu) | (vr_[1] << 16);
    u32 lo1 = (vr_[2] & 0xFFFFu) | (vr_[3] << 16);
    u32 lo2 = (vr_[4] & 0xFFFFu) | (vr_[5] << 16);
    u32 lo3 = (vr_[6] & 0xFFFFu) | (vr_[7] << 16);
    u32 hh0 = (vr_[0] >> 16) | (vr_[1] & 0xFFFF0000u);
    u32 hh1 = (vr_[2] >> 16) | (vr_[3] & 0xFFFF0000u);
    u32 hh2 = (vr_[4] >> 16) | (vr_[5] & 0xFFFF0000u);
    u32 hh3 = (vr_[6] >> 16) | (vr_[7] & 0xFFFF0000u);
    const int d1 = vd0 + 1;
    u32x4 vlo = {lo0, lo1, lo2, lo3};
    u32x4 vhi = {hh0, hh1, hh2, hh3};
    *(u32x4*)(VtB + ((vd0 * 128 + vkey0 * 2) ^ ((vd0 & 7) << 4))) = vlo;
    *(u32x4*)(VtB + ((d1 * 128 + vkey0 * 2) ^ ((d1 & 7) << 4))) = vhi;
  };

  const int ksw2 = (cc & 7) << 4;

  // QK^T for one chunk (kf passed in regs)
  auto QKT = [&](short8 (&kf)[4][2], const short8& qa0, const short8& qa1,
                 f32x4 (&s)[4]) {
#pragma unroll
    for (int nt = 0; nt < 4; ++nt) {
      f32x4 z = f32x4{0.f, 0.f, 0.f, 0.f};
      z = MFMA32(kf[nt][0], qa0, z);
      z = MFMA32(kf[nt][1], qa1, z);
      s[nt] = z;
    }
  };

  // softmax + P-stage for one chunk
  auto SM = [&](f32x4 (&s)[4], float& mrow, float& lsum, f32x4* o, char* PsX) {
    float tm = s[0][0];
#pragma unroll
    for (int nt = 0; nt < 4; ++nt)
#pragma unroll
      for (int r = 0; r < 4; ++r) tm = fmaxf(tm, s[nt][r]);
    tm = fmaxf(tm, __shfl_xor(tm, 16));
    tm = fmaxf(tm, __shfl_xor(tm, 32));
    const bool need = tm > mrow + 8.0f;      // defer-max
    float corr = 1.0f;
    if (need) { corr = exp2f(mrow - tm); mrow = tm; }
    float psum = 0.f;
#pragma unroll
    for (int nt = 0; nt < 4; ++nt) {
      float e0 = exp2f(s[nt][0] - mrow);
      float e1 = exp2f(s[nt][1] - mrow);
      float e2 = exp2f(s[nt][2] - mrow);
      float e3 = exp2f(s[nt][3] - mrow);
      psum += (e0 + e1) + (e2 + e3);
      u32 pr[2] = { pk_bf16(e0, e1), pk_bf16(e2, e3) };
      *(u64*)(PsX + ((cc * 128 + nt * 32 + hi * 8) ^ ksw2)) = *(const u64*)pr;
    }
    psum += __shfl_xor(psum, 16);
    psum += __shfl_xor(psum, 32);
    lsum = lsum * corr + psum;
    if (__any(need)) {
#pragma unroll
      for (int nt = 0; nt < 4; ++nt) o[nt] *= corr;
    }
  };

  auto MASK = [&](f32x4 (&s)[4]) {
    const int qloc = w * 16 + cc;
#pragma unroll
    for (int nt = 0; nt < 4; ++nt)
#pragma unroll
      for (int r = 0; r < 4; ++r)
        if (nt * 16 + hi4 + r > qloc) s[nt][r] = -1e30f;
  };

  // prologue: stage tile 0, prefetch tile 1
  LOADT(0);
  WRITET();
  LOADT(1);                       // qtB >= 16, always more than 1 tile
  __syncthreads();

  for (int kt = 0; kt <= qtB; ++kt) {
    short8 kf[4][2];
#pragma unroll
    for (int nt = 0; nt < 4; ++nt) {
      const int kb = (nt * 16 + cc) * 128 + hi * 16;
      kf[nt][0] = *(const short8*)(KsB + (kb ^ ksw2));
      kf[nt][1] = *(const short8*)(KsB + ((kb + 64) ^ ksw2));
    }

    const bool actA = (kt <= qtA);
    f32x4 sB[4], sA[4];
    QKT(kf, qaB0, qaB1, sB);
    if (actA) QKT(kf, qaA0, qaA1, sA);
    if (kt == qtB) MASK(sB);
    if (actA && kt == qtA) MASK(sA);

    SM(sB, mB, lB, oB, PsB_);
    if (actA) SM(sA, mA, lA, oA, PsA_);

    // V fragments, read once, shared by both chunks
    short8 vf[2][4];
#pragma unroll
    for (int kc = 0; kc < 2; ++kc)
#pragma unroll
      for (int nt = 0; nt < 4; ++nt)
        vf[kc][nt] = *(const short8*)(VtB + (((nt * 16 + cc) * 128 + kc * 64 + hi * 16) ^ ksw2));

#pragma unroll
    for (int kc = 0; kc < 2; ++kc) {
      short8 pa = *(const short8*)(PsB_ + ((cc * 128 + kc * 64 + hi * 16) ^ ksw2));
#pragma unroll
      for (int nt = 0; nt < 4; ++nt)
        oB[nt] = MFMA32(vf[kc][nt], pa, oB[nt]);
    }
    if (actA) {
#pragma unroll
      for (int kc = 0; kc < 2; ++kc) {
        short8 pa = *(const short8*)(PsA_ + ((cc * 128 + kc * 64 + hi * 16) ^ ksw2));
#pragma unroll
        for (int nt = 0; nt < 4; ++nt)
          oA[nt] = MFMA32(vf[kc][nt], pa, oA[nt]);
      }
    }

    if (kt < qtB) {
      __syncthreads();             // all waves done reading Ks/Vt
      WRITET();                    // stage tile kt+1 (regs from last LOADT)
      if (kt + 1 < qtB) LOADT(kt + 2);   // prefetch tile kt+2
      __syncthreads();             // staged tile visible
    }
  }

  const float ivA = 1.0f / lA, ivB = 1.0f / lB;
#pragma unroll
  for (int nt = 0; nt < 4; ++nt) {
    u16x4 yA = { f2bf(oA[nt][0] * ivA), f2bf(oA[nt][1] * ivA),
                 f2bf(oA[nt][2] * ivA), f2bf(oA[nt][3] * ivA) };
    *(u16x4*)(Yb + hbase + (size_t)(qA0w + cc) * C + nt * 16 + hi4) = yA;
    u16x4 yB = { f2bf(oB[nt][0] * ivB), f2bf(oB[nt][1] * ivB),
                 f2bf(oB[nt][2] * ivB), f2bf(oB[nt][3] * ivB) };
    *(u16x4*)(Yb + hbase + (size_t)(qB0w + cc) * C + nt * 16 + hi4) = yB;
  }
}

// ---------------- proj GEMM: BN=64, BK=64, fp32 out, swizzled LDS ----------------
__global__ __launch_bounds__(256, 2) void gemm_proj(
    const u16* __restrict__ A, const u16* __restrict__ W,
    const float* __restrict__ bias, float* __restrict__ Out) {
  const int K = 1024, N = 1024;
  __shared__ __attribute__((aligned(16))) u16 As[128 * 64];
  __shared__ __attribute__((aligned(16))) u16 Bs[64 * 64];
  const int tid = threadIdx.x;
  const int lane = tid & 63;
  const int hi = lane >> 4, cc = lane & 15;
  const int w = tid >> 6, wm = w >> 1, wn = w & 1;
  const int row0 = blockIdx.y * 128, col0 = blockIdx.x * 64;

  const int lr = tid >> 3;
  const int lkb = (((tid & 7) ^ (lr & 7)) * 8);
  const u16* Ag = A + (size_t)(row0 + lr) * K + lkb;
  const u16* Wg = W + (size_t)(col0 + lr) * K + lkb;

  f32x4 acc[4][2];
#pragma unroll
  for (int m = 0; m < 4; ++m)
#pragma unroll
    for (int n = 0; n < 2; ++n) acc[m][n] = f32x4{0.f, 0.f, 0.f, 0.f};

  for (int k0 = 0; k0 < K; k0 += 64) {
    __syncthreads();
#pragma unroll
    for (int j = 0; j < 4; ++j)
      gl_lds16(Ag + (size_t)j * 32 * K + k0, As + j * 2048 + tid * 8);
#pragma unroll
    for (int j = 0; j < 2; ++j)
      gl_lds16(Wg + (size_t)j * 32 * K + k0, Bs + j * 2048 + tid * 8);
    __syncthreads();
    short8 a[2][4], b[2][2];
#pragma unroll
    for (int kk = 0; kk < 2; ++kk) {
#pragma unroll
      for (int m = 0; m < 4; ++m)
        a[kk][m] = *(const short8*)(As + (wm * 64 + m * 16 + cc) * 64 +
                                    (((kk * 4 + hi) ^ (cc & 7)) * 8));
#pragma unroll
      for (int n = 0; n < 2; ++n)
        b[kk][n] = *(const short8*)(Bs + (wn * 32 + n * 16 + cc) * 64 +
                                    (((kk * 4 + hi) ^ (cc & 7)) * 8));
    }
#pragma unroll
    for (int kk = 0; kk < 2; ++kk)
#pragma unroll
      for (int m = 0; m < 4; ++m)
#pragma unroll
        for (int n = 0; n < 2; ++n)
          acc[m][n] = MFMA32(a[kk][m], b[kk][n], acc[m][n]);
  }

#pragma unroll
  for (int n = 0; n < 2; ++n) {
    const int col = col0 + wn * 32 + n * 16 + cc;
    const float bb = bias[col];
#pragma unroll
    for (int m = 0; m < 4; ++m) {
      const int rw = row0 + wm * 64 + m * 16 + hi * 4;
#pragma unroll
      for (int r = 0; r < 4; ++r)
        Out[(size_t)(rw + r) * N + col] = acc[m][n][r] + bb;
    }
  }
}

extern "C" void kernel_launch(void* const* d_in, const int* in_sizes, int n_in,
                              void* d_out, int out_size, void* d_ws, size_t ws_size,
                              hipStream_t stream) {
  const float* x  = (const float*)d_in[0];
  const float* Wq = (const float*)d_in[1];
  const float* bq = (const float*)d_in[2];
  const float* Wk = (const float*)d_in[3];
  const float* bk = (const float*)d_in[4];
  const float* Wv = (const float*)d_in[5];
  const float* bv = (const float*)d_in[6];
  const float* Wp = (const float*)d_in[7];
  const float* bp = (const float*)d_in[8];
  float* out = (float*)d_out;

  const int B = 2, T = 2048, C = 1024;
  const int M = B * T;
  const size_t MC = (size_t)M * C;
  const size_t CC = (size_t)C * C;

  char* p = (char*)d_ws;
  u16* xb  = (u16*)p;  p += MC * 2;    // reused as Y after QKV GEMM
  u16* Wqb = (u16*)p;  p += CC * 2;
  u16* Wkb = (u16*)p;  p += CC * 2;
  u16* Wvb = (u16*)p;  p += CC * 2;
  u16* Wpb = (u16*)p;  p += CC * 2;
  u16* Qbb = (u16*)p;  p += MC * 2;
  u16* Kbb = (u16*)p;  p += MC * 2;
  u16* Vbb = (u16*)p;  p += MC * 2;
  float* cosT = (float*)p; p += (size_t)T * 32 * 4;
  float* sinT = (float*)p; p += (size_t)T * 32 * 4;

  const int n4x = (int)(MC / 4);
  const int n4tot = n4x + 4 * (int)(CC / 4);
  const int ntot = n4tot + T * 32;     // + RoPE table items
  cvt_all<<<(ntot + 255) / 256, 256, 0, stream>>>(x, Wq, Wk, Wv, Wp,
                                                  xb, Wqb, Wkb, Wvb, Wpb,
                                                  cosT, sinT, n4x, n4tot);

  dim3 gq(24, M / 128);
  gemm_qkv<<<gq, 256, 0, stream>>>(xb, Wqb, Wkb, Wvb, bq, bk, bv, cosT, sinT, Qbb, Kbb, Vbb);

  dim3 fg(16, B * 16);
  flash_mfma<<<fg, 256, 0, stream>>>(Qbb, Kbb, Vbb, xb);   // Y -> xb (reuse)

  dim3 gp(C / 64, M / 128);
  gemm_proj<<<gp, 256, 0, stream>>>(xb, Wpb, bp, out);
}

// Round 14
// 123.476 us; speedup vs baseline: 1.4263x; 1.0056x over previous
//
#include <hip/hip_runtime.h>
#include <math.h>

typedef unsigned short u16;
typedef unsigned int u32;
typedef unsigned long long u64;
typedef __attribute__((ext_vector_type(8))) short short8;
typedef __attribute__((ext_vector_type(4))) float f32x4;
typedef __attribute__((ext_vector_type(4))) u16 u16x4;
typedef __attribute__((ext_vector_type(4))) u32 u32x4;

#define AS1 __attribute__((address_space(1)))
#define AS3 __attribute__((address_space(3)))

// 0.125 * log2(e): QK^T scores scaled so softmax = exp2
#define QSCALE 0.18033688011112042f

__device__ __forceinline__ u16 f2bf(float f) {
  union { float f; u32 i; } u; u.f = f;
  u32 r = u.i + 0x7FFFu + ((u.i >> 16) & 1u);
  return (u16)(r >> 16);
}

__device__ __forceinline__ u32 pk_bf16(float a, float b) {
  u32 r;
  asm volatile("v_cvt_pk_bf16_f32 %0, %1, %2" : "=v"(r) : "v"(a), "v"(b));
  return r;
}

__device__ __forceinline__ void gl_lds16(const void* g, void* l) {
  __builtin_amdgcn_global_load_lds((const AS1 u32*)g, (AS3 u32*)l, 16, 0, 0);
}

#define MFMA32(a, b, c) __builtin_amdgcn_mfma_f32_16x16x32_bf16(a, b, c, 0, 0, 0)

// ---------------- fused convert (x + 4 weights) + RoPE table ----------------
__global__ void cvt_all(const float* __restrict__ x,
                        const float* __restrict__ Wq, const float* __restrict__ Wk,
                        const float* __restrict__ Wv, const float* __restrict__ Wp,
                        u16* __restrict__ xb,
                        u16* __restrict__ Wqb, u16* __restrict__ Wkb,
                        u16* __restrict__ Wvb, u16* __restrict__ Wpb,
                        float* __restrict__ cosT, float* __restrict__ sinT,
                        int n4x, int n4tot) {
  int i = blockIdx.x * 256 + threadIdx.x;
  if (i >= n4tot) {                    // RoPE table tail: 65536 items
    int k = i - n4tot;
    int t = k >> 5, j = k & 31;
    float inv = powf(10000.0f, -(float)j / 32.0f);
    float ang = (float)t * inv;
    cosT[k] = cosf(ang);
    sinT[k] = sinf(ang);
    return;
  }
  const float* src; u16* dst; int off;
  if (i < n4x) { src = x; dst = xb; off = i; }
  else {
    int wi = i - n4x;
    int sel = wi >> 18;                // CC/4 = 2^18
    off = wi & ((1 << 18) - 1);
    src = sel == 0 ? Wq : sel == 1 ? Wk : sel == 2 ? Wv : Wp;
    dst = sel == 0 ? Wqb : sel == 1 ? Wkb : sel == 2 ? Wvb : Wpb;
  }
  float4 v = ((const float4*)src)[off];
  u16x4 o = { f2bf(v.x), f2bf(v.y), f2bf(v.z), f2bf(v.w) };
  ((u16x4*)dst)[off] = o;
}

// ---------------- fused QKV GEMM (bf16 MFMA), BK=64, RoPE epilogue ----------------
// XCD-aware remap: lin = a + 8*(b + 3*r), a=XCD gets (sel,colt) group c=a*3+b
// -> per-XCD weight working set 3 col-tiles (768 KB, L2-resident).
__global__ __launch_bounds__(256, 2) void gemm_qkv(
    const u16* __restrict__ xb,
    const u16* __restrict__ Wqb, const u16* __restrict__ Wkb, const u16* __restrict__ Wvb,
    const float* __restrict__ bq, const float* __restrict__ bk, const float* __restrict__ bv,
    const float* __restrict__ cosT, const float* __restrict__ sinT,
    u16* __restrict__ Qb, u16* __restrict__ Kb, u16* __restrict__ Vb) {
  const int K = 1024, N = 1024;
  __shared__ __attribute__((aligned(16))) u16 As[128 * 64];
  __shared__ __attribute__((aligned(16))) u16 Bs[128 * 64];
  const int tid = threadIdx.x;
  const int lane = tid & 63;
  const int hi = lane >> 4, cc = lane & 15;
  const int w = tid >> 6, wm = w >> 1, wn = w & 1;

  const int lin = blockIdx.x + 24 * blockIdx.y;   // gridDim (24, 32)
  const int a_ = lin & 7;
  const int m_ = lin >> 3;
  const int c_ = a_ * 3 + (m_ % 3);               // 0..23: sel*8 + colt
  const int sel = c_ >> 3;
  const int row0 = (m_ / 3) * 128, col0 = (c_ & 7) * 128;

  const u16* W = sel == 0 ? Wqb : sel == 1 ? Wkb : Wvb;
  const float* bias = sel == 0 ? bq : sel == 1 ? bk : bv;
  u16* Out = sel == 0 ? Qb : sel == 1 ? Kb : Vb;

  const int lr = tid >> 3;                                   // 0..31
  const int lkb = (((tid & 7) ^ (lr & 7)) * 8);              // pre-swizzled src col
  const u16* Ag = xb + (size_t)(row0 + lr) * K + lkb;
  const u16* Wg = W + (size_t)(col0 + lr) * K + lkb;

  f32x4 acc[4][4];
#pragma unroll
  for (int m = 0; m < 4; ++m)
#pragma unroll
    for (int n = 0; n < 4; ++n) acc[m][n] = f32x4{0.f, 0.f, 0.f, 0.f};

  for (int k0 = 0; k0 < K; k0 += 64) {
    __syncthreads();
#pragma unroll
    for (int j = 0; j < 4; ++j) {
      gl_lds16(Ag + (size_t)j * 32 * K + k0, As + j * 2048 + tid * 8);
      gl_lds16(Wg + (size_t)j * 32 * K + k0, Bs + j * 2048 + tid * 8);
    }
    __syncthreads();
    short8 a[2][4], b[2][4];
#pragma unroll
    for (int kk = 0; kk < 2; ++kk) {
#pragma unroll
      for (int m = 0; m < 4; ++m)
        a[kk][m] = *(const short8*)(As + (wm * 64 + m * 16 + cc) * 64 +
                                    (((kk * 4 + hi) ^ (cc & 7)) * 8));
#pragma unroll
      for (int n = 0; n < 4; ++n)
        b[kk][n] = *(const short8*)(Bs + (wn * 64 + n * 16 + cc) * 64 +
                                    (((kk * 4 + hi) ^ (cc & 7)) * 8));
    }
#pragma unroll
    for (int kk = 0; kk < 2; ++kk)
#pragma unroll
      for (int m = 0; m < 4; ++m)
#pragma unroll
        for (int n = 0; n < 4; ++n)
          acc[m][n] = MFMA32(a[kk][m], b[kk][n], acc[m][n]);
  }

  if (sel < 2) {
    const float qs = (sel == 0) ? QSCALE : 1.0f;
#pragma unroll
    for (int n = 0; n < 4; ++n) {
      const int col = col0 + wn * 64 + n * 16 + cc;
      const int j = (col & 63) >> 1;
      const float bb = bias[col];
#pragma unroll
      for (int m = 0; m < 4; ++m) {
        const int rw = row0 + wm * 64 + m * 16 + hi * 4;
#pragma unroll
        for (int r = 0; r < 4; ++r) {
          const int row = rw + r;
          const int t = row & 2047;
          float v = acc[m][n][r] + bb;
          float pv = __shfl_xor(v, 1);
          float c = cosT[t * 32 + j], s = sinT[t * 32 + j];
          float oo = (cc & 1) ? (s * pv + c * v) : (c * v - s * pv);
          Out[(size_t)row * N + col] = f2bf(oo * qs);
        }
      }
    }
  } else {
#pragma unroll
    for (int n = 0; n < 4; ++n) {
      const int col = col0 + wn * 64 + n * 16 + cc;
      const float bb = bias[col];
#pragma unroll
      for (int m = 0; m < 4; ++m) {
        const int rw = row0 + wm * 64 + m * 16 + hi * 4;
#pragma unroll
        for (int r = 0; r < 4; ++r)
          Out[(size_t)(rw + r) * N + col] = f2bf(acc[m][n][r] + bb);
      }
    }
  }
}

// ---------------- MFMA causal flash attention: balanced pairing, XCD-local bh ----------------
// lin = a + 8*(b + 4*r): XCD a gets bh = 4a+b (4 heads -> 2 MB K/V, L2-resident),
// qtA = r. Chunks qtA / 31-qtA; phase-interleaved (R13 structure, proven).
__global__ __launch_bounds__(256, 2) void flash_mfma(
    const u16* __restrict__ Qb, const u16* __restrict__ Kb,
    const u16* __restrict__ Vb, u16* __restrict__ Yb) {
  const int T = 2048, C = 1024;
  __shared__ __attribute__((aligned(16))) u16 Ks[64 * 64];        // swizzled [key][d]
  __shared__ __attribute__((aligned(16))) u16 Vt[64 * 64];        // swizzled [d][key]
  __shared__ __attribute__((aligned(16))) u16 Ps[4][2][16 * 64];  // [wave][chunk] P[q][key]

  const int tid = threadIdx.x;
  const int lane = tid & 63;
  const int hi = lane >> 4, cc = lane & 15;
  const int hi4 = hi * 4;
  const int w = tid >> 6;

  const int lin = blockIdx.x + 16 * blockIdx.y;   // gridDim (16, 32)
  const int bh  = (lin & 7) * 4 + ((lin >> 3) & 3);
  const int qtA = lin >> 5;          // 0..15
  const int qtB = 31 - qtA;          // 16..31
  const size_t hbase = (size_t)(bh >> 4) * T * C + (size_t)(bh & 15) * 64;
  const int qA0w = qtA * 64 + w * 16;
  const int qB0w = qtB * 64 + w * 16;

  short8 qaA0, qaA1, qaB0, qaB1;
  {
    const u16* qp = Qb + hbase + (size_t)(qA0w + cc) * C + hi * 8;
    qaA0 = *(const short8*)qp;
    qaA1 = *(const short8*)(qp + 32);
    qp = Qb + hbase + (size_t)(qB0w + cc) * C + hi * 8;
    qaB0 = *(const short8*)qp;
    qaB1 = *(const short8*)(qp + 32);
  }

  f32x4 oA[4], oB[4];
#pragma unroll
  for (int nt = 0; nt < 4; ++nt) {
    oA[nt] = f32x4{0.f, 0.f, 0.f, 0.f};
    oB[nt] = f32x4{0.f, 0.f, 0.f, 0.f};
  }
  float mA = -1e30f, lA = 0.f, mB = -1e30f, lB = 0.f;

  const int krow = tid >> 2, kcol = (tid & 3) * 16;
  const int vd0 = (tid & 31) * 2, vkey0 = (tid >> 5) * 8;
  const u16* kgp = Kb + hbase + (size_t)krow * C + kcol;
  const u16* vgp = Vb + hbase + (size_t)vkey0 * C + vd0;

  short8 kr0, kr1;
  u32 vr_[8];

  auto LOADT = [&](int kt) {
    const size_t off = (size_t)(kt * 64) * C;
    kr0 = *(const short8*)(kgp + off);
    kr1 = *(const short8*)(kgp + off + 8);
#pragma unroll
    for (int j = 0; j < 8; ++j)
      vr_[j] = *(const u32*)(vgp + off + (size_t)j * C);
  };

  char* KsB = (char*)Ks;
  char* VtB = (char*)Vt;
  char* PsA_ = (char*)(Ps[w][0]);
  char* PsB_ = (char*)(Ps[w][1]);

  auto WRITET = [&]() {
    const int kb = krow * 128 + kcol * 2;
    const int ksw = (krow & 7) << 4;
    *(short8*)(KsB + (kb ^ ksw)) = kr0;
    *(short8*)(KsB + ((kb + 16) ^ ksw)) = kr1;
    u32 lo0 = (vr_[0] & 0xFFFFu) | (vr_[1] << 16);
    u32 lo1 = (vr_[2] & 0xFFFFu) | (vr_[3] << 16);
    u32 lo2 = (vr_[4] & 0xFFFFu) | (vr_[5] << 16);
    u32 lo3 = (vr_[6] & 0xFFFFu) | (vr_[7] << 16);
    u32 hh0 = (vr_[0] >> 16) | (vr_[1] & 0xFFFF0000u);
    u32 hh1 = (vr_[2] >> 16) | (vr_[3] & 0xFFFF0000u);
    u32 hh2 = (vr_[4] >> 16) | (vr_[5] & 0xFFFF0000u);
    u32 hh3 = (vr_[6] >> 16) | (vr_[7] & 0xFFFF0000u);
    const int d1 = vd0 + 1;
    u32x4 vlo = {lo0, lo1, lo2, lo3};
    u32x4 vhi = {hh0, hh1, hh2, hh3};
    *(u32x4*)(VtB + ((vd0 * 128 + vkey0 * 2) ^ ((vd0 & 7) << 4))) = vlo;
    *(u32x4*)(VtB + ((d1 * 128 + vkey0 * 2) ^ ((d1 & 7) << 4))) = vhi;
  };

  const int ksw2 = (cc & 7) << 4;

  auto QKT = [&](short8 (&kf)[4][2], const short8& qa0, const short8& qa1,
                 f32x4 (&s)[4]) {
#pragma unroll
    for (int nt = 0; nt < 4; ++nt) {
      f32x4 z = f32x4{0.f, 0.f, 0.f, 0.f};
      z = MFMA32(kf[nt][0], qa0, z);
      z = MFMA32(kf[nt][1], qa1, z);
      s[nt] = z;
    }
  };

  auto SM = [&](f32x4 (&s)[4], float& mrow, float& lsum, f32x4* o, char* PsX) {
    float tm = s[0][0];
#pragma unroll
    for (int nt = 0; nt < 4; ++nt)
#pragma unroll
      for (int r = 0; r < 4; ++r) tm = fmaxf(tm, s[nt][r]);
    tm = fmaxf(tm, __shfl_xor(tm, 16));
    tm = fmaxf(tm, __shfl_xor(tm, 32));
    const bool need = tm > mrow + 8.0f;      // defer-max
    float corr = 1.0f;
    if (need) { corr = exp2f(mrow - tm); mrow = tm; }
    float psum = 0.f;
#pragma unroll
    for (int nt = 0; nt < 4; ++nt) {
      float e0 = exp2f(s[nt][0] - mrow);
      float e1 = exp2f(s[nt][1] - mrow);
      float e2 = exp2f(s[nt][2] - mrow);
      float e3 = exp2f(s[nt][3] - mrow);
      psum += (e0 + e1) + (e2 + e3);
      u32 pr[2] = { pk_bf16(e0, e1), pk_bf16(e2, e3) };
      *(u64*)(PsX + ((cc * 128 + nt * 32 + hi * 8) ^ ksw2)) = *(const u64*)pr;
    }
    psum += __shfl_xor(psum, 16);
    psum += __shfl_xor(psum, 32);
    lsum = lsum * corr + psum;
    if (__any(need)) {
#pragma unroll
      for (int nt = 0; nt < 4; ++nt) o[nt] *= corr;
    }
  };

  auto MASK = [&](f32x4 (&s)[4]) {
    const int qloc = w * 16 + cc;
#pragma unroll
    for (int nt = 0; nt < 4; ++nt)
#pragma unroll
      for (int r = 0; r < 4; ++r)
        if (nt * 16 + hi4 + r > qloc) s[nt][r] = -1e30f;
  };

  // prologue: stage tile 0, prefetch tile 1
  LOADT(0);
  WRITET();
  LOADT(1);                       // qtB >= 16, always more than 1 tile
  __syncthreads();

  for (int kt = 0; kt <= qtB; ++kt) {
    short8 kf[4][2];
#pragma unroll
    for (int nt = 0; nt < 4; ++nt) {
      const int kb = (nt * 16 + cc) * 128 + hi * 16;
      kf[nt][0] = *(const short8*)(KsB + (kb ^ ksw2));
      kf[nt][1] = *(const short8*)(KsB + ((kb + 64) ^ ksw2));
    }

    const bool actA = (kt <= qtA);
    f32x4 sB[4], sA[4];
    QKT(kf, qaB0, qaB1, sB);
    if (actA) QKT(kf, qaA0, qaA1, sA);
    if (kt == qtB) MASK(sB);
    if (actA && kt == qtA) MASK(sA);

    SM(sB, mB, lB, oB, PsB_);
    if (actA) SM(sA, mA, lA, oA, PsA_);

    // V fragments, read once, shared by both chunks
    short8 vf[2][4];
#pragma unroll
    for (int kc = 0; kc < 2; ++kc)
#pragma unroll
      for (int nt = 0; nt < 4; ++nt)
        vf[kc][nt] = *(const short8*)(VtB + (((nt * 16 + cc) * 128 + kc * 64 + hi * 16) ^ ksw2));

#pragma unroll
    for (int kc = 0; kc < 2; ++kc) {
      short8 pa = *(const short8*)(PsB_ + ((cc * 128 + kc * 64 + hi * 16) ^ ksw2));
#pragma unroll
      for (int nt = 0; nt < 4; ++nt)
        oB[nt] = MFMA32(vf[kc][nt], pa, oB[nt]);
    }
    if (actA) {
#pragma unroll
      for (int kc = 0; kc < 2; ++kc) {
        short8 pa = *(const short8*)(PsA_ + ((cc * 128 + kc * 64 + hi * 16) ^ ksw2));
#pragma unroll
        for (int nt = 0; nt < 4; ++nt)
          oA[nt] = MFMA32(vf[kc][nt], pa, oA[nt]);
      }
    }

    if (kt < qtB) {
      __syncthreads();             // all waves done reading Ks/Vt
      WRITET();                    // stage tile kt+1 (regs from last LOADT)
      if (kt + 1 < qtB) LOADT(kt + 2);   // prefetch tile kt+2
      __syncthreads();             // staged tile visible
    }
  }

  const float ivA = 1.0f / lA, ivB = 1.0f / lB;
#pragma unroll
  for (int nt = 0; nt < 4; ++nt) {
    u16x4 yA = { f2bf(oA[nt][0] * ivA), f2bf(oA[nt][1] * ivA),
                 f2bf(oA[nt][2] * ivA), f2bf(oA[nt][3] * ivA) };
    *(u16x4*)(Yb + hbase + (size_t)(qA0w + cc) * C + nt * 16 + hi4) = yA;
    u16x4 yB = { f2bf(oB[nt][0] * ivB), f2bf(oB[nt][1] * ivB),
                 f2bf(oB[nt][2] * ivB), f2bf(oB[nt][3] * ivB) };
    *(u16x4*)(Yb + hbase + (size_t)(qB0w + cc) * C + nt * 16 + hi4) = yB;
  }
}

// ---------------- proj GEMM: BN=64, BK=64, fp32 out, swizzled LDS, XCD remap ----------------
__global__ __launch_bounds__(256, 2) void gemm_proj(
    const u16* __restrict__ A, const u16* __restrict__ W,
    const float* __restrict__ bias, float* __restrict__ Out) {
  const int K = 1024, N = 1024;
  __shared__ __attribute__((aligned(16))) u16 As[128 * 64];
  __shared__ __attribute__((aligned(16))) u16 Bs[64 * 64];
  const int tid = threadIdx.x;
  const int lane = tid & 63;
  const int hi = lane >> 4, cc = lane & 15;
  const int w = tid >> 6, wm = w >> 1, wn = w & 1;

  const int lin = blockIdx.x + 16 * blockIdx.y;   // gridDim (16, 32)
  const int colt = (lin & 7) * 2 + ((lin >> 3) & 1);
  const int row0 = (lin >> 4) * 128, col0 = colt * 64;

  const int lr = tid >> 3;
  const int lkb = (((tid & 7) ^ (lr & 7)) * 8);
  const u16* Ag = A + (size_t)(row0 + lr) * K + lkb;
  const u16* Wg = W + (size_t)(col0 + lr) * K + lkb;

  f32x4 acc[4][2];
#pragma unroll
  for (int m = 0; m < 4; ++m)
#pragma unroll
    for (int n = 0; n < 2; ++n) acc[m][n] = f32x4{0.f, 0.f, 0.f, 0.f};

  for (int k0 = 0; k0 < K; k0 += 64) {
    __syncthreads();
#pragma unroll
    for (int j = 0; j < 4; ++j)
      gl_lds16(Ag + (size_t)j * 32 * K + k0, As + j * 2048 + tid * 8);
#pragma unroll
    for (int j = 0; j < 2; ++j)
      gl_lds16(Wg + (size_t)j * 32 * K + k0, Bs + j * 2048 + tid * 8);
    __syncthreads();
    short8 a[2][4], b[2][2];
#pragma unroll
    for (int kk = 0; kk < 2; ++kk) {
#pragma unroll
      for (int m = 0; m < 4; ++m)
        a[kk][m] = *(const short8*)(As + (wm * 64 + m * 16 + cc) * 64 +
                                    (((kk * 4 + hi) ^ (cc & 7)) * 8));
#pragma unroll
      for (int n = 0; n < 2; ++n)
        b[kk][n] = *(const short8*)(Bs + (wn * 32 + n * 16 + cc) * 64 +
                                    (((kk * 4 + hi) ^ (cc & 7)) * 8));
    }
#pragma unroll
    for (int kk = 0; kk < 2; ++kk)
#pragma unroll
      for (int m = 0; m < 4; ++m)
#pragma unroll
        for (int n = 0; n < 2; ++n)
          acc[m][n] = MFMA32(a[kk][m], b[kk][n], acc[m][n]);
  }

#pragma unroll
  for (int n = 0; n < 2; ++n) {
    const int col = col0 + wn * 32 + n * 16 + cc;
    const float bb = bias[col];
#pragma unroll
    for (int m = 0; m < 4; ++m) {
      const int rw = row0 + wm * 64 + m * 16 + hi * 4;
#pragma unroll
      for (int r = 0; r < 4; ++r)
        Out[(size_t)(rw + r) * N + col] = acc[m][n][r] + bb;
    }
  }
}

extern "C" void kernel_launch(void* const* d_in, const int* in_sizes, int n_in,
                              void* d_out, int out_size, void* d_ws, size_t ws_size,
                              hipStream_t stream) {
  const float* x  = (const float*)d_in[0];
  const float* Wq = (const float*)d_in[1];
  const float* bq = (const float*)d_in[2];
  const float* Wk = (const float*)d_in[3];
  const float* bk = (const float*)d_in[4];
  const float* Wv = (const float*)d_in[5];
  const float* bv = (const float*)d_in[6];
  const float* Wp = (const float*)d_in[7];
  const float* bp = (const float*)d_in[8];
  float* out = (float*)d_out;

  const int B = 2, T = 2048, C = 1024;
  const int M = B * T;
  const size_t MC = (size_t)M * C;
  const size_t CC = (size_t)C * C;

  char* p = (char*)d_ws;
  u16* xb  = (u16*)p;  p += MC * 2;    // reused as Y after QKV GEMM
  u16* Wqb = (u16*)p;  p += CC * 2;
  u16* Wkb = (u16*)p;  p += CC * 2;
  u16* Wvb = (u16*)p;  p += CC * 2;
  u16* Wpb = (u16*)p;  p += CC * 2;
  u16* Qbb = (u16*)p;  p += MC * 2;
  u16* Kbb = (u16*)p;  p += MC * 2;
  u16* Vbb = (u16*)p;  p += MC * 2;
  float* cosT = (float*)p; p += (size_t)T * 32 * 4;
  float* sinT = (float*)p; p += (size_t)T * 32 * 4;

  const int n4x = (int)(MC / 4);
  const int n4tot = n4x + 4 * (int)(CC / 4);
  const int ntot = n4tot + T * 32;     // + RoPE table items
  cvt_all<<<(ntot + 255) / 256, 256, 0, stream>>>(x, Wq, Wk, Wv, Wp,
                                                  xb, Wqb, Wkb, Wvb, Wpb,
                                                  cosT, sinT, n4x, n4tot);

  dim3 gq(24, M / 128);
  gemm_qkv<<<gq, 256, 0, stream>>>(xb, Wqb, Wkb, Wvb, bq, bk, bv, cosT, sinT, Qbb, Kbb, Vbb);

  dim3 fg(16, B * 16);
  flash_mfma<<<fg, 256, 0, stream>>>(Qbb, Kbb, Vbb, xb);   // Y -> xb (reuse)

  dim3 gp(C / 64, M / 128);
  gemm_proj<<<gp, 256, 0, stream>>>(xb, Wpb, bp, out);
}